// Round 3
// baseline (139.059 us; speedup 1.0000x reference)
//
#include <hip/hip_runtime.h>
#include <hip/hip_bf16.h>
#include <math.h>

#define Hd   1024
#define Bsz  4096
#define Kc   3072      // concatenated K (3 x 1024)
#define NT   48        // K-tiles of 64

typedef unsigned short u16;
typedef __attribute__((ext_vector_type(8))) u16 u16x8;
typedef __attribute__((ext_vector_type(2))) u16 u16x2;
typedef __attribute__((ext_vector_type(16))) float f32x16;
typedef __attribute__((ext_vector_type(8))) short bf16x8;

template<bool V> struct BoolC { static constexpr bool value = V; };

__device__ inline u16 f2bf(float f) {
    __hip_bfloat16 h = __float2bfloat16(f);
    return *reinterpret_cast<u16*>(&h);
}

__device__ inline float sigm(float x) { return 1.0f / (1.0f + __expf(-x)); }

__device__ inline void gload16(const void* g, const void* s) {
    __builtin_amdgcn_global_load_lds(
        (const __attribute__((address_space(1))) void*)g,
        (__attribute__((address_space(3))) void*)s, 16, 0, 0);
}

#define BAR()   __builtin_amdgcn_s_barrier()
#define VMW(n)  asm volatile("s_waitcnt vmcnt(" #n ")" ::: "memory")

// ---------------------------------------------------------------------------
// prep_A: A_cat bf16 [4096][3072], row m' = 4*r + gate  <-  src row gate*1024+r
// Block 0 additionally zeroes the z-row accumulator region of out.
// ---------------------------------------------------------------------------
__global__ __launch_bounds__(256) void prep_A(const float* __restrict__ U11,
                                              const float* __restrict__ U21,
                                              const float* __restrict__ W01,
                                              u16* __restrict__ Ab,
                                              float* __restrict__ out) {
    if (blockIdx.x == 0) {
        float* outz = out + (size_t)2 * Hd * Bsz;
        for (int i = threadIdx.x; i < Bsz; i += 256) outz[i] = 0.0f;
    }
    int t = blockIdx.x * 256 + threadIdx.x;
    int row = t / 384;
    int kc = (t - row * 384) * 8;
    int r = row >> 2, gate = row & 3;
    int sel = kc >> 10;
    int k = kc & 1023;
    const float* src = (sel == 0) ? W01 : ((sel == 1) ? U21 : U11);
    const float4* p = reinterpret_cast<const float4*>(src + (size_t)(gate * Hd + r) * Hd + k);
    float4 v0 = p[0], v1 = p[1];
    u16x8 o;
    o[0] = f2bf(v0.x); o[1] = f2bf(v0.y); o[2] = f2bf(v0.z); o[3] = f2bf(v0.w);
    o[4] = f2bf(v1.x); o[5] = f2bf(v1.y); o[6] = f2bf(v1.z); o[7] = f2bf(v1.w);
    *reinterpret_cast<u16x8*>(Ab + (size_t)row * Kc + kc) = o;
}

// ---------------------------------------------------------------------------
// prep_B: B_catT bf16 [4096(n)][3072(k')]  (transpose + per-column z gating)
// Fused: z-row partial dot-products (w_row4096 . src) accumulated via atomicAdd.
// ---------------------------------------------------------------------------
__global__ __launch_bounds__(256) void prep_B(const float* __restrict__ hb,
                                              const float* __restrict__ ht,
                                              const float* __restrict__ hh,
                                              const float* __restrict__ z,
                                              const float* __restrict__ zb,
                                              const float* __restrict__ U11,
                                              const float* __restrict__ U21,
                                              const float* __restrict__ W01,
                                              u16* __restrict__ Bb,
                                              float* __restrict__ out) {
    __shared__ float tile[64][33];
    __shared__ float red[8][32];
    int n0 = blockIdx.x * 32;
    int kg0 = blockIdx.y * 64;
    int sel = kg0 >> 10;
    int k0 = kg0 & 1023;
    const float* src = (sel == 0) ? hb : ((sel == 1) ? ht : hh);
    const float* wsrc = (sel == 0) ? W01 : ((sel == 1) ? U21 : U11);
    int t = threadIdx.x, tx = t & 31, ty = t >> 5;
#pragma unroll
    for (int j = 0; j < 8; ++j) {
        int kk = ty * 8 + j;
        tile[kk][tx] = src[(size_t)(k0 + kk) * Bsz + n0 + tx];
    }
    __syncthreads();
    {   // bf16 transpose+gate write (unchanged)
        int kp = t & 31, ny = t >> 5;
#pragma unroll
        for (int j = 0; j < 4; ++j) {
            int nl = ny * 4 + j;
            int n = n0 + nl;
            float s = (sel == 0) ? 1.0f : ((sel == 1) ? z[n] : zb[n]);
            u16x2 o;
            o[0] = f2bf(tile[kp * 2][nl] * s);
            o[1] = f2bf(tile[kp * 2 + 1][nl] * s);
            *reinterpret_cast<u16x2*>(Bb + (size_t)n * Kc + kg0 + kp * 2) = o;
        }
    }
    {   // fused z-row partial: sum_k w[k0+kk] * tile[kk][col], scaled by gate
        int col = t & 31, seg = t >> 5;
        const float* w = wsrc + (size_t)4096 * 1024 + k0 + seg * 8;
        float p = 0.0f;
#pragma unroll
        for (int j = 0; j < 8; ++j) p += w[j] * tile[seg * 8 + j][col];
        red[seg][col] = p;
        __syncthreads();
        if (seg == 0) {
            float tot = 0.0f;
#pragma unroll
            for (int q = 0; q < 8; ++q) tot += red[q][col];
            int n = n0 + col;
            float sca = (sel == 0) ? 1.0f : ((sel == 1) ? z[n] : zb[n]);
            atomicAdd(out + (size_t)2 * Hd * Bsz + n, tot * sca);
        }
    }
}

// ---------------------------------------------------------------------------
// gemm_fused: 256x256 tile, BK=64, 8 waves, 4-phase counted schedule with
// one-phase-ahead LDS reads, 32x32x16 bf16 MFMA, XOR-swizzled LDS,
// fused LSTM epilogue. bm==0 blocks finalize the z-row.
// ---------------------------------------------------------------------------
__global__ __launch_bounds__(512, 2) void gemm_fused(
    const u16* __restrict__ A, const u16* __restrict__ Bm,
    const float* __restrict__ c_in, const float* __restrict__ h_in,
    const float* __restrict__ z, const float* __restrict__ zb,
    const float* __restrict__ bias, float* __restrict__ out) {
    extern __shared__ __align__(16) u16 smem[];
    u16* const AsB = smem;            // [2][256*64]
    u16* const BsB = smem + 32768;    // [2][256*64]

    const int t = threadIdx.x;
    const int w = t >> 6, l = t & 63;
    const int wm = w >> 2, wn = w & 3;
    const int c = l & 31, hi = l >> 5, key = l & 7;

    const int orig = blockIdx.x;                  // 256 wgs, bijective XCD swizzle
    const int wg = ((orig & 7) << 5) | (orig >> 3);
    const int bm = wg >> 4, bn = wg & 15;

    const int srow = t >> 3;                      // staging row within an issue
    const int sgs  = (t & 7) ^ (srow & 7);        // pre-swizzled source granule

    f32x16 accum[4][2];                           // [mh*2+mb][nh]
#pragma unroll
    for (int i = 0; i < 4; ++i)
#pragma unroll
        for (int j = 0; j < 2; ++j)
#pragma unroll
            for (int e = 0; e < 16; ++e) accum[i][j][e] = 0.0f;

    const u16* gA = A  + (size_t)(bm * 256 + srow) * Kc + sgs * 8;
    const u16* gB = Bm + (size_t)(bn * 256 + srow) * Kc + sgs * 8;

    auto stageA = [&](int buf, int half, int kt) {
#pragma unroll
        for (int iss = 0; iss < 2; ++iss) {
            const u16* g = gA + (size_t)(half * 128 + iss * 64) * Kc + kt * 64;
            const u16* d = AsB + buf * 16384 + (half * 128 + iss * 64 + (w << 3)) * 64;
            gload16(g, d);
        }
    };
    auto stageB = [&](int buf, int half, int kt) {
#pragma unroll
        for (int iss = 0; iss < 2; ++iss) {
            const u16* g = gB + (size_t)(half * 128 + iss * 64) * Kc + kt * 64;
            const u16* d = BsB + buf * 16384 + (half * 128 + iss * 64 + (w << 3)) * 64;
            gload16(g, d);
        }
    };

    bf16x8 aF[2][2][4];   // [mh][mb][ks]
    bf16x8 bQ0[4], bQ1[4];

    auto rdA = [&](const u16* base, int mh, int mb, int ks) -> bf16x8 {
        int row = mh * 128 + wm * 64 + mb * 32 + c;
        int slot = (2 * ks + hi) ^ key;
        return *reinterpret_cast<const bf16x8*>(base + row * 64 + slot * 8);
    };
    auto rdB = [&](const u16* base, int nh, int ks) -> bf16x8 {
        int row = nh * 128 + wn * 32 + c;
        int slot = (2 * ks + hi) ^ key;
        return *reinterpret_cast<const bf16x8*>(base + row * 64 + slot * 8);
    };

    // prologue: stage tile 0 halves in consumption order A0,B0,A1,B1
    stageA(0, 0, 0); stageB(0, 0, 0); stageA(0, 1, 0); stageB(0, 1, 0);
    VMW(2); BAR();

    auto ktile = [&](int tc, auto pfc) {
        constexpr bool pf = decltype(pfc)::value;
        const int cur = tc & 1, nxt = cur ^ 1;
        const u16* Ac = AsB + cur * 16384;
        const u16* Bc = BsB + cur * 16384;
        // ---- phase 0: MFMA (mh0,nh0); reads A0,B0 + ahead A1
        if constexpr (pf) stageA(nxt, 0, tc + 1);
#pragma unroll
        for (int mb = 0; mb < 2; ++mb)
#pragma unroll
            for (int ks = 0; ks < 4; ++ks) aF[0][mb][ks] = rdA(Ac, 0, mb, ks);
#pragma unroll
        for (int ks = 0; ks < 4; ++ks) bQ0[ks] = rdB(Bc, 0, ks);
#pragma unroll
        for (int mb = 0; mb < 2; ++mb)
#pragma unroll
            for (int ks = 0; ks < 4; ++ks) aF[1][mb][ks] = rdA(Ac, 1, mb, ks);
        BAR();
        __builtin_amdgcn_s_setprio(1);
#pragma unroll
        for (int mb = 0; mb < 2; ++mb)
#pragma unroll
            for (int ks = 0; ks < 4; ++ks)
                accum[mb][0] = __builtin_amdgcn_mfma_f32_32x32x16_bf16(
                    aF[0][mb][ks], bQ0[ks], accum[mb][0], 0, 0, 0);
        __builtin_amdgcn_s_setprio(0);
        if constexpr (pf) { VMW(2); } else { VMW(0); }   // B1(cur) ready for ph1
        BAR();
        // ---- phase 1: MFMA (mh1,nh0); reads ahead B1
        if constexpr (pf) stageB(nxt, 0, tc + 1);
#pragma unroll
        for (int ks = 0; ks < 4; ++ks) bQ1[ks] = rdB(Bc, 1, ks);
        BAR();
        __builtin_amdgcn_s_setprio(1);
#pragma unroll
        for (int mb = 0; mb < 2; ++mb)
#pragma unroll
            for (int ks = 0; ks < 4; ++ks)
                accum[2 + mb][0] = __builtin_amdgcn_mfma_f32_32x32x16_bf16(
                    aF[1][mb][ks], bQ0[ks], accum[2 + mb][0], 0, 0, 0);
        __builtin_amdgcn_s_setprio(0);
        BAR();
        // ---- phase 2: MFMA (mh1,nh1); no reads
        if constexpr (pf) stageA(nxt, 1, tc + 1);
        BAR();
        __builtin_amdgcn_s_setprio(1);
#pragma unroll
        for (int mb = 0; mb < 2; ++mb)
#pragma unroll
            for (int ks = 0; ks < 4; ++ks)
                accum[2 + mb][1] = __builtin_amdgcn_mfma_f32_32x32x16_bf16(
                    aF[1][mb][ks], bQ1[ks], accum[2 + mb][1], 0, 0, 0);
        __builtin_amdgcn_s_setprio(0);
        BAR();
        // ---- phase 3: MFMA (mh0,nh1); no reads
        if constexpr (pf) stageB(nxt, 1, tc + 1);
        BAR();
        __builtin_amdgcn_s_setprio(1);
#pragma unroll
        for (int mb = 0; mb < 2; ++mb)
#pragma unroll
            for (int ks = 0; ks < 4; ++ks)
                accum[mb][1] = __builtin_amdgcn_mfma_f32_32x32x16_bf16(
                    aF[0][mb][ks], bQ1[ks], accum[mb][1], 0, 0, 0);
        __builtin_amdgcn_s_setprio(0);
        if constexpr (pf) { VMW(2); }   // A0,B0,A1(next) ready for next ph0
        BAR();
    };

    for (int tc = 0; tc < NT - 1; ++tc) ktile(tc, BoolC<true>{});
    ktile(NT - 1, BoolC<false>{});

    // fused LSTM epilogue: reg-quad q of each 32x32 block = f,i,o,g of one unit
    float zc[2], zbv[2];
#pragma unroll
    for (int nh = 0; nh < 2; ++nh) {
        int n = bn * 256 + nh * 128 + wn * 32 + c;
        zc[nh] = z[n]; zbv[nh] = zb[n];
    }
#pragma unroll
    for (int mh = 0; mh < 2; ++mh)
#pragma unroll
        for (int mb = 0; mb < 2; ++mb) {
            const int u0 = bm * 64 + mh * 32 + wm * 16 + mb * 8;
#pragma unroll
            for (int nh = 0; nh < 2; ++nh) {
                const int n = bn * 256 + nh * 128 + wn * 32 + c;
                const float zcv = zc[nh], zbvv = zbv[nh];
                const float nz = 1.0f - zcv, nzb = 1.0f - zbvv;
                f32x16 a = accum[mh * 2 + mb][nh];
#pragma unroll
                for (int q = 0; q < 4; ++q) {
                    const int r = u0 + 2 * q + hi;
                    const float co = c_in[(size_t)r * Bsz + n];
                    const float ho = h_in[(size_t)r * Bsz + n];
                    float fg = sigm(a[4 * q + 0] + bias[r]);
                    float ig = sigm(a[4 * q + 1] + bias[Hd + r]);
                    float og = sigm(a[4 * q + 2] + bias[2 * Hd + r]);
                    float gg = tanhf(a[4 * q + 3] + bias[3 * Hd + r]);
                    float i_g = ig * gg;
                    float cn = zcv * i_g + nz * nzb * co + nz * zbvv * (fg * co + i_g);
                    float tc2 = tanhf(cn);
                    float hn = zcv * og * tc2 + nz * nzb * ho + nz * zbvv * og * tc2;
                    out[(size_t)r * Bsz + n] = hn;
                    out[(size_t)Hd * Bsz + (size_t)r * Bsz + n] = cn;
                }
            }
        }

    // z-row finalize (16 blocks with bm==0 cover all 4096 columns)
    if (bm == 0 && t < 256) {
        float* outz = out + (size_t)2 * Hd * Bsz;
        int n = bn * 256 + t;
        float s = outz[n] + bias[4096];
        float zh = (s + 1.0f) * 0.5f;
        zh = fminf(fmaxf(zh, 0.0f), 1.0f);
        outz[n] = (zh > 0.5f) ? 1.0f : 0.0f;
    }
}

extern "C" void kernel_launch(void* const* d_in, const int* in_sizes, int n_in,
                              void* d_out, int out_size, void* d_ws, size_t ws_size,
                              hipStream_t stream) {
    (void)in_sizes; (void)n_in; (void)out_size; (void)ws_size;
    const float* c    = (const float*)d_in[0];
    const float* hb   = (const float*)d_in[1];
    const float* h    = (const float*)d_in[2];
    const float* ht   = (const float*)d_in[3];
    const float* z    = (const float*)d_in[4];
    const float* zb   = (const float*)d_in[5];
    const float* U11  = (const float*)d_in[6];
    const float* U21  = (const float*)d_in[7];
    const float* W01  = (const float*)d_in[8];
    const float* bias = (const float*)d_in[9];
    float* out = (float*)d_out;

    u16* Ab = (u16*)d_ws;                          // 25.2 MB
    u16* Bb = Ab + (size_t)4096 * Kc;              // 25.2 MB

    hipFuncSetAttribute(reinterpret_cast<const void*>(gemm_fused),
                        hipFuncAttributeMaxDynamicSharedMemorySize, 131072);

    prep_A<<<6144, 256, 0, stream>>>(U11, U21, W01, Ab, out);
    prep_B<<<dim3(128, 48), 256, 0, stream>>>(hb, ht, h, z, zb, U11, U21, W01, Bb, out);
    gemm_fused<<<256, 512, 131072, stream>>>(Ab, Bb, c, h, z, zb, bias, out);
}

// Round 4
// 121.817 us; speedup vs baseline: 1.1415x; 1.1415x over previous
//
#include <hip/hip_runtime.h>
#include <hip/hip_bf16.h>
#include <math.h>

#define Hd   1024
#define Bsz  4096
#define Kc   3072      // concatenated K (3 x 1024)
#define NT   48        // K-tiles of 64

typedef unsigned short u16;
typedef __attribute__((ext_vector_type(8))) u16 u16x8;
typedef __attribute__((ext_vector_type(2))) u16 u16x2;
typedef __attribute__((ext_vector_type(4))) float f32x4;
typedef __attribute__((ext_vector_type(8))) short bf16x8;

template<bool V> struct BoolC { static constexpr bool value = V; };

__device__ inline u16 f2bf(float f) {
    __hip_bfloat16 h = __float2bfloat16(f);
    return *reinterpret_cast<u16*>(&h);
}

__device__ inline float sigm(float x) { return 1.0f / (1.0f + __expf(-x)); }

__device__ inline void gload16(const void* g, const void* s) {
    __builtin_amdgcn_global_load_lds(
        (const __attribute__((address_space(1))) void*)g,
        (__attribute__((address_space(3))) void*)s, 16, 0, 0);
}

#define BAR()   __builtin_amdgcn_s_barrier()
#define VMW(n)  asm volatile("s_waitcnt vmcnt(" #n ")" ::: "memory")

// ---------------------------------------------------------------------------
// prep_A: A_cat bf16 [4096][3072], row m' = 4*r + gate  <-  src row gate*1024+r
// Block 0 additionally zeroes the z-row accumulator region of out.
// ---------------------------------------------------------------------------
__global__ __launch_bounds__(256) void prep_A(const float* __restrict__ U11,
                                              const float* __restrict__ U21,
                                              const float* __restrict__ W01,
                                              u16* __restrict__ Ab,
                                              float* __restrict__ out) {
    if (blockIdx.x == 0) {
        float* outz = out + (size_t)2 * Hd * Bsz;
        for (int i = threadIdx.x; i < Bsz; i += 256) outz[i] = 0.0f;
    }
    int t = blockIdx.x * 256 + threadIdx.x;
    int row = t / 384;
    int kc = (t - row * 384) * 8;
    int r = row >> 2, gate = row & 3;
    int sel = kc >> 10;
    int k = kc & 1023;
    const float* src = (sel == 0) ? W01 : ((sel == 1) ? U21 : U11);
    const float4* p = reinterpret_cast<const float4*>(src + (size_t)(gate * Hd + r) * Hd + k);
    float4 v0 = p[0], v1 = p[1];
    u16x8 o;
    o[0] = f2bf(v0.x); o[1] = f2bf(v0.y); o[2] = f2bf(v0.z); o[3] = f2bf(v0.w);
    o[4] = f2bf(v1.x); o[5] = f2bf(v1.y); o[6] = f2bf(v1.z); o[7] = f2bf(v1.w);
    *reinterpret_cast<u16x8*>(Ab + (size_t)row * Kc + kc) = o;
}

// ---------------------------------------------------------------------------
// prep_B: B_catT bf16 [4096(n)][3072(k')]  (transpose + per-column z gating)
// Fused: z-row partial dot-products (w_row4096 . src) accumulated via atomicAdd.
// ---------------------------------------------------------------------------
__global__ __launch_bounds__(256) void prep_B(const float* __restrict__ hb,
                                              const float* __restrict__ ht,
                                              const float* __restrict__ hh,
                                              const float* __restrict__ z,
                                              const float* __restrict__ zb,
                                              const float* __restrict__ U11,
                                              const float* __restrict__ U21,
                                              const float* __restrict__ W01,
                                              u16* __restrict__ Bb,
                                              float* __restrict__ out) {
    __shared__ float tile[64][33];
    __shared__ float red[8][32];
    int n0 = blockIdx.x * 32;
    int kg0 = blockIdx.y * 64;
    int sel = kg0 >> 10;
    int k0 = kg0 & 1023;
    const float* src = (sel == 0) ? hb : ((sel == 1) ? ht : hh);
    const float* wsrc = (sel == 0) ? W01 : ((sel == 1) ? U21 : U11);
    int t = threadIdx.x, tx = t & 31, ty = t >> 5;
#pragma unroll
    for (int j = 0; j < 8; ++j) {
        int kk = ty * 8 + j;
        tile[kk][tx] = src[(size_t)(k0 + kk) * Bsz + n0 + tx];
    }
    __syncthreads();
    {   // bf16 transpose+gate write
        int kp = t & 31, ny = t >> 5;
#pragma unroll
        for (int j = 0; j < 4; ++j) {
            int nl = ny * 4 + j;
            int n = n0 + nl;
            float s = (sel == 0) ? 1.0f : ((sel == 1) ? z[n] : zb[n]);
            u16x2 o;
            o[0] = f2bf(tile[kp * 2][nl] * s);
            o[1] = f2bf(tile[kp * 2 + 1][nl] * s);
            *reinterpret_cast<u16x2*>(Bb + (size_t)n * Kc + kg0 + kp * 2) = o;
        }
    }
    {   // fused z-row partial
        int col = t & 31, seg = t >> 5;
        const float* w = wsrc + (size_t)4096 * 1024 + k0 + seg * 8;
        float p = 0.0f;
#pragma unroll
        for (int j = 0; j < 8; ++j) p += w[j] * tile[seg * 8 + j][col];
        red[seg][col] = p;
        __syncthreads();
        if (seg == 0) {
            float tot = 0.0f;
#pragma unroll
            for (int q = 0; q < 8; ++q) tot += red[q][col];
            int n = n0 + col;
            float sca = (sel == 0) ? 1.0f : ((sel == 1) ? z[n] : zb[n]);
            atomicAdd(out + (size_t)2 * Hd * Bsz + n, tot * sca);
        }
    }
}

// ---------------------------------------------------------------------------
// gemm_fused: 256x256 tile, BK=64, 8 waves, 16x16x32 MFMA, XOR-swizzled LDS
// (R2 layout: 0 bank conflicts), 4 phases/tile with fragment read-ahead and
// only 2 counted vmcnt waits per tile. Fused LSTM epilogue; bm==0 blocks
// finalize the z-row.
// Phase order (mh,nh): (0,0),(1,0),(1,1),(0,1).
//   ph0: stage A0'; read A0,B0 frags (own) + A1 frags (ahead); MFMA; VMW(2)
//   ph1: stage B0'; read B1 frags (ahead); MFMA
//   ph2: stage A1'; MFMA
//   ph3: stage B1'; MFMA; VMW(2)  -> next tile's A0,B0,A1 complete
// ---------------------------------------------------------------------------
__global__ __launch_bounds__(512, 2) void gemm_fused(
    const u16* __restrict__ A, const u16* __restrict__ Bm,
    const float* __restrict__ c_in, const float* __restrict__ h_in,
    const float* __restrict__ z, const float* __restrict__ zb,
    const float* __restrict__ bias, float* __restrict__ out) {
    extern __shared__ __align__(16) u16 smem[];
    u16* const AsB = smem;            // [2][256*64]
    u16* const BsB = smem + 32768;    // [2][256*64]

    const int t = threadIdx.x;
    const int w = t >> 6, l = t & 63;
    const int wm = w >> 2, wn = w & 3;

    const int orig = blockIdx.x;                  // 256 wgs, bijective XCD swizzle
    const int wg = ((orig & 7) << 5) | (orig >> 3);
    const int bm = wg >> 4, bn = wg & 15;

    const int srow = t >> 3;                      // staging row within an issue
    const int sgs  = (t & 7) ^ (srow & 7);        // pre-swizzled source granule
    const int fr = l & 15, fq = l >> 4, fkey = l & 7;

    f32x4 acc[8][4];
#pragma unroll
    for (int i = 0; i < 8; ++i)
#pragma unroll
        for (int j = 0; j < 4; ++j) acc[i][j] = (f32x4){0.f, 0.f, 0.f, 0.f};

    const u16* gA = A  + (size_t)(bm * 256 + srow) * Kc + sgs * 8;
    const u16* gB = Bm + (size_t)(bn * 256 + srow) * Kc + sgs * 8;

    auto stageA = [&](int buf, int half, int kt) {
#pragma unroll
        for (int iss = 0; iss < 2; ++iss) {
            const u16* g = gA + (size_t)(half * 128 + iss * 64) * Kc + kt * 64;
            const u16* d = AsB + buf * 16384 + (half * 128 + iss * 64 + (w << 3)) * 64;
            gload16(g, d);
        }
    };
    auto stageB = [&](int buf, int half, int kt) {
#pragma unroll
        for (int iss = 0; iss < 2; ++iss) {
            const u16* g = gB + (size_t)(half * 128 + iss * 64) * Kc + kt * 64;
            const u16* d = BsB + buf * 16384 + (half * 128 + iss * 64 + (w << 3)) * 64;
            gload16(g, d);
        }
    };

    bf16x8 aF[2][4][2];   // [mh][miL][ks]
    bf16x8 bF[2][2][2];   // [nh][niL][ks]

    auto readA = [&](int buf, int mh, int miL, int ks) -> bf16x8 {
        int r = mh * 128 + wm * 64 + miL * 16 + fr;
        int g = ((ks << 2) + fq) ^ fkey;
        return *reinterpret_cast<const bf16x8*>(AsB + buf * 16384 + r * 64 + g * 8);
    };
    auto readB = [&](int buf, int nh, int niL, int ks) -> bf16x8 {
        int r = nh * 128 + wn * 32 + niL * 16 + fr;
        int g = ((ks << 2) + fq) ^ fkey;
        return *reinterpret_cast<const bf16x8*>(BsB + buf * 16384 + r * 64 + g * 8);
    };

    // prologue: stage tile 0 halves; A0,B0,A1 must be complete (B1 may fly)
    stageA(0, 0, 0); stageB(0, 0, 0); stageA(0, 1, 0); stageB(0, 1, 0);
    VMW(2); BAR();

    auto ktile = [&](int tc, auto pfc) {
        constexpr bool pf = decltype(pfc)::value;
        const int cur = tc & 1, nxt = cur ^ 1;
        // ---- phase 0: MFMA (mh0,nh0); reads A0,B0 (own) + A1 (ahead)
        if constexpr (pf) stageA(nxt, 0, tc + 1);
#pragma unroll
        for (int mi = 0; mi < 4; ++mi) {
            aF[0][mi][0] = readA(cur, 0, mi, 0); aF[0][mi][1] = readA(cur, 0, mi, 1);
        }
#pragma unroll
        for (int ni = 0; ni < 2; ++ni) {
            bF[0][ni][0] = readB(cur, 0, ni, 0); bF[0][ni][1] = readB(cur, 0, ni, 1);
        }
#pragma unroll
        for (int mi = 0; mi < 4; ++mi) {
            aF[1][mi][0] = readA(cur, 1, mi, 0); aF[1][mi][1] = readA(cur, 1, mi, 1);
        }
        BAR();
        __builtin_amdgcn_s_setprio(1);
#pragma unroll
        for (int mi = 0; mi < 4; ++mi)
#pragma unroll
            for (int ni = 0; ni < 2; ++ni)
#pragma unroll
                for (int ks = 0; ks < 2; ++ks)
                    acc[mi][ni] = __builtin_amdgcn_mfma_f32_16x16x32_bf16(
                        aF[0][mi][ks], bF[0][ni][ks], acc[mi][ni], 0, 0, 0);
        __builtin_amdgcn_s_setprio(0);
        if constexpr (pf) { VMW(2); } else { VMW(0); }   // B1(cur) complete
        BAR();
        // ---- phase 1: MFMA (mh1,nh0); reads B1 (ahead)
        if constexpr (pf) stageB(nxt, 0, tc + 1);
#pragma unroll
        for (int ni = 0; ni < 2; ++ni) {
            bF[1][ni][0] = readB(cur, 1, ni, 0); bF[1][ni][1] = readB(cur, 1, ni, 1);
        }
        BAR();
        __builtin_amdgcn_s_setprio(1);
#pragma unroll
        for (int mi = 0; mi < 4; ++mi)
#pragma unroll
            for (int ni = 0; ni < 2; ++ni)
#pragma unroll
                for (int ks = 0; ks < 2; ++ks)
                    acc[4 + mi][ni] = __builtin_amdgcn_mfma_f32_16x16x32_bf16(
                        aF[1][mi][ks], bF[0][ni][ks], acc[4 + mi][ni], 0, 0, 0);
        __builtin_amdgcn_s_setprio(0);
        BAR();
        // ---- phase 2: MFMA (mh1,nh1); no reads
        if constexpr (pf) stageA(nxt, 1, tc + 1);
        BAR();
        __builtin_amdgcn_s_setprio(1);
#pragma unroll
        for (int mi = 0; mi < 4; ++mi)
#pragma unroll
            for (int ni = 0; ni < 2; ++ni)
#pragma unroll
                for (int ks = 0; ks < 2; ++ks)
                    acc[4 + mi][2 + ni] = __builtin_amdgcn_mfma_f32_16x16x32_bf16(
                        aF[1][mi][ks], bF[1][ni][ks], acc[4 + mi][2 + ni], 0, 0, 0);
        __builtin_amdgcn_s_setprio(0);
        BAR();
        // ---- phase 3: MFMA (mh0,nh1); no reads
        if constexpr (pf) stageB(nxt, 1, tc + 1);
        BAR();
        __builtin_amdgcn_s_setprio(1);
#pragma unroll
        for (int mi = 0; mi < 4; ++mi)
#pragma unroll
            for (int ni = 0; ni < 2; ++ni)
#pragma unroll
                for (int ks = 0; ks < 2; ++ks)
                    acc[mi][2 + ni] = __builtin_amdgcn_mfma_f32_16x16x32_bf16(
                        aF[0][mi][ks], bF[1][ni][ks], acc[mi][2 + ni], 0, 0, 0);
        __builtin_amdgcn_s_setprio(0);
        if constexpr (pf) { VMW(2); }   // A0,B0,A1(next) complete
        BAR();
    };

    for (int tc = 0; tc < NT - 1; ++tc) ktile(tc, BoolC<true>{});
    ktile(NT - 1, BoolC<false>{});

    // fused LSTM epilogue: acc[mi][ni] regs = f,i,o,g of unit r, col n
    const int rB = bm * 64;
    const int nB = bn * 256;
    float zc[4], zbv[4];
#pragma unroll
    for (int ni = 0; ni < 4; ++ni) {
        int n = nB + (ni >> 1) * 128 + wn * 32 + (ni & 1) * 16 + fr;
        zc[ni] = z[n]; zbv[ni] = zb[n];
    }
#pragma unroll
    for (int mi = 0; mi < 8; ++mi) {
        const int r = rB + (mi >> 2) * 32 + wm * 16 + (mi & 3) * 4 + fq;
        const float b0 = bias[r], b1 = bias[Hd + r], b2 = bias[2 * Hd + r], b3 = bias[3 * Hd + r];
        const float* crow = c_in + (size_t)r * Bsz;
        const float* hrow = h_in + (size_t)r * Bsz;
        float* hout = out + (size_t)r * Bsz;
        float* cout = out + (size_t)Hd * Bsz + (size_t)r * Bsz;
#pragma unroll
        for (int ni = 0; ni < 4; ++ni) {
            const int n = nB + (ni >> 1) * 128 + wn * 32 + (ni & 1) * 16 + fr;
            f32x4 a = acc[mi][ni];
            float co = crow[n], ho = hrow[n];
            float fg = sigm(a[0] + b0);
            float ig = sigm(a[1] + b1);
            float og = sigm(a[2] + b2);
            float gg = tanhf(a[3] + b3);
            float i_g = ig * gg;
            float nz = 1.0f - zc[ni], nzb = 1.0f - zbv[ni];
            float cn = zc[ni] * i_g + nz * nzb * co + nz * zbv[ni] * (fg * co + i_g);
            float tc2 = tanhf(cn);
            float hn = zc[ni] * og * tc2 + nz * nzb * ho + nz * zbv[ni] * og * tc2;
            hout[n] = hn; cout[n] = cn;
        }
    }

    // z-row finalize (16 blocks with bm==0 cover all 4096 columns)
    if (bm == 0 && t < 256) {
        float* outz = out + (size_t)2 * Hd * Bsz;
        int n = bn * 256 + t;
        float s = outz[n] + bias[4096];
        float zh = (s + 1.0f) * 0.5f;
        zh = fminf(fmaxf(zh, 0.0f), 1.0f);
        outz[n] = (zh > 0.5f) ? 1.0f : 0.0f;
    }
}

extern "C" void kernel_launch(void* const* d_in, const int* in_sizes, int n_in,
                              void* d_out, int out_size, void* d_ws, size_t ws_size,
                              hipStream_t stream) {
    (void)in_sizes; (void)n_in; (void)out_size; (void)ws_size;
    const float* c    = (const float*)d_in[0];
    const float* hb   = (const float*)d_in[1];
    const float* h    = (const float*)d_in[2];
    const float* ht   = (const float*)d_in[3];
    const float* z    = (const float*)d_in[4];
    const float* zb   = (const float*)d_in[5];
    const float* U11  = (const float*)d_in[6];
    const float* U21  = (const float*)d_in[7];
    const float* W01  = (const float*)d_in[8];
    const float* bias = (const float*)d_in[9];
    float* out = (float*)d_out;

    u16* Ab = (u16*)d_ws;                          // 25.2 MB
    u16* Bb = Ab + (size_t)4096 * Kc;              // 25.2 MB

    hipFuncSetAttribute(reinterpret_cast<const void*>(gemm_fused),
                        hipFuncAttributeMaxDynamicSharedMemorySize, 131072);

    prep_A<<<6144, 256, 0, stream>>>(U11, U21, W01, Ab, out);
    prep_B<<<dim3(128, 48), 256, 0, stream>>>(hb, ht, h, z, zb, U11, U21, W01, Bb, out);
    gemm_fused<<<256, 512, 131072, stream>>>(Ab, Bb, c, h, z, zb, bias, out);
}

// Round 5
// 120.120 us; speedup vs baseline: 1.1577x; 1.0141x over previous
//
#include <hip/hip_runtime.h>
#include <hip/hip_bf16.h>
#include <math.h>

#define Hd   1024
#define Bsz  4096
#define Kc   3072      // concatenated K (3 x 1024)
#define NT   48        // K-tiles of 64

typedef unsigned short u16;
typedef __attribute__((ext_vector_type(8))) u16 u16x8;
typedef __attribute__((ext_vector_type(2))) u16 u16x2;
typedef __attribute__((ext_vector_type(4))) float f32x4;
typedef __attribute__((ext_vector_type(8))) short bf16x8;

template<bool V> struct BoolC { static constexpr bool value = V; };

__device__ inline u16 f2bf(float f) {
    __hip_bfloat16 h = __float2bfloat16(f);
    return *reinterpret_cast<u16*>(&h);
}

__device__ inline float sigm(float x) { return 1.0f / (1.0f + __expf(-x)); }

__device__ inline void gload16(const void* g, const void* s) {
    __builtin_amdgcn_global_load_lds(
        (const __attribute__((address_space(1))) void*)g,
        (__attribute__((address_space(3))) void*)s, 16, 0, 0);
}

#define BAR()   __builtin_amdgcn_s_barrier()
#define VMW(n)  asm volatile("s_waitcnt vmcnt(" #n ")" ::: "memory")

// ---------------------------------------------------------------------------
// prep_A: A_cat bf16 [4096][3072], row m' = 4*r + gate  <-  src row gate*1024+r
// Block 0 additionally zeroes the z-row accumulator region of out.
// ---------------------------------------------------------------------------
__global__ __launch_bounds__(256) void prep_A(const float* __restrict__ U11,
                                              const float* __restrict__ U21,
                                              const float* __restrict__ W01,
                                              u16* __restrict__ Ab,
                                              float* __restrict__ out) {
    if (blockIdx.x == 0) {
        float* outz = out + (size_t)2 * Hd * Bsz;
        for (int i = threadIdx.x; i < Bsz; i += 256) outz[i] = 0.0f;
    }
    int t = blockIdx.x * 256 + threadIdx.x;
    int row = t / 384;
    int kc = (t - row * 384) * 8;
    int r = row >> 2, gate = row & 3;
    int sel = kc >> 10;
    int k = kc & 1023;
    const float* src = (sel == 0) ? W01 : ((sel == 1) ? U21 : U11);
    const float4* p = reinterpret_cast<const float4*>(src + (size_t)(gate * Hd + r) * Hd + k);
    float4 v0 = p[0], v1 = p[1];
    u16x8 o;
    o[0] = f2bf(v0.x); o[1] = f2bf(v0.y); o[2] = f2bf(v0.z); o[3] = f2bf(v0.w);
    o[4] = f2bf(v1.x); o[5] = f2bf(v1.y); o[6] = f2bf(v1.z); o[7] = f2bf(v1.w);
    *reinterpret_cast<u16x8*>(Ab + (size_t)row * Kc + kc) = o;
}

// ---------------------------------------------------------------------------
// prep_B: B_catT bf16 [4096(n)][3072(k')]  (transpose + per-column z gating)
// Fused: z-row partial dot-products (w_row4096 . src) accumulated via atomicAdd.
// ---------------------------------------------------------------------------
__global__ __launch_bounds__(256) void prep_B(const float* __restrict__ hb,
                                              const float* __restrict__ ht,
                                              const float* __restrict__ hh,
                                              const float* __restrict__ z,
                                              const float* __restrict__ zb,
                                              const float* __restrict__ U11,
                                              const float* __restrict__ U21,
                                              const float* __restrict__ W01,
                                              u16* __restrict__ Bb,
                                              float* __restrict__ out) {
    __shared__ float tile[64][33];
    __shared__ float red[8][32];
    int n0 = blockIdx.x * 32;
    int kg0 = blockIdx.y * 64;
    int sel = kg0 >> 10;
    int k0 = kg0 & 1023;
    const float* src = (sel == 0) ? hb : ((sel == 1) ? ht : hh);
    const float* wsrc = (sel == 0) ? W01 : ((sel == 1) ? U21 : U11);
    int t = threadIdx.x, tx = t & 31, ty = t >> 5;
#pragma unroll
    for (int j = 0; j < 8; ++j) {
        int kk = ty * 8 + j;
        tile[kk][tx] = src[(size_t)(k0 + kk) * Bsz + n0 + tx];
    }
    __syncthreads();
    {   // bf16 transpose+gate write
        int kp = t & 31, ny = t >> 5;
#pragma unroll
        for (int j = 0; j < 4; ++j) {
            int nl = ny * 4 + j;
            int n = n0 + nl;
            float s = (sel == 0) ? 1.0f : ((sel == 1) ? z[n] : zb[n]);
            u16x2 o;
            o[0] = f2bf(tile[kp * 2][nl] * s);
            o[1] = f2bf(tile[kp * 2 + 1][nl] * s);
            *reinterpret_cast<u16x2*>(Bb + (size_t)n * Kc + kg0 + kp * 2) = o;
        }
    }
    {   // fused z-row partial
        int col = t & 31, seg = t >> 5;
        const float* w = wsrc + (size_t)4096 * 1024 + k0 + seg * 8;
        float p = 0.0f;
#pragma unroll
        for (int j = 0; j < 8; ++j) p += w[j] * tile[seg * 8 + j][col];
        red[seg][col] = p;
        __syncthreads();
        if (seg == 0) {
            float tot = 0.0f;
#pragma unroll
            for (int q = 0; q < 8; ++q) tot += red[q][col];
            int n = n0 + col;
            float sca = (sel == 0) ? 1.0f : ((sel == 1) ? z[n] : zb[n]);
            atomicAdd(out + (size_t)2 * Hd * Bsz + n, tot * sca);
        }
    }
}

// ---------------------------------------------------------------------------
// gemm_fused: 256x256 tile, BK=64, 8 waves, 16x16x32 MFMA, XOR-swizzled LDS
// (0 bank conflicts), deep-pipelined 4-phase schedule:
//   stage next tile EARLY (ph0: A0',B0'; ph1: A1',B1') -> every half-tile has
//   4-5 phases in flight; guards are counted VMW(4)/(6)/(8) at the phase that
//   first reads that half-tile (never drain mid-loop).
// Frag reads 12/8/4/0 per phase; ph3 is reg-only (no barrier).
// Fused LSTM epilogue; bm==0 blocks finalize the z-row.
// ---------------------------------------------------------------------------
__global__ __launch_bounds__(512, 2) void gemm_fused(
    const u16* __restrict__ A, const u16* __restrict__ Bm,
    const float* __restrict__ c_in, const float* __restrict__ h_in,
    const float* __restrict__ z, const float* __restrict__ zb,
    const float* __restrict__ bias, float* __restrict__ out) {
    extern __shared__ __align__(16) u16 smem[];
    u16* const AsB = smem;            // [2][256*64]
    u16* const BsB = smem + 32768;    // [2][256*64]

    const int t = threadIdx.x;
    const int w = t >> 6, l = t & 63;
    const int wm = w >> 2, wn = w & 3;

    const int orig = blockIdx.x;                  // 256 wgs, bijective XCD swizzle
    const int wg = ((orig & 7) << 5) | (orig >> 3);
    const int bm = wg >> 4, bn = wg & 15;

    const int srow = t >> 3;                      // staging row within an issue
    const int sgs  = (t & 7) ^ (srow & 7);        // pre-swizzled source granule
    const int fr = l & 15, fq = l >> 4, fkey = l & 7;

    f32x4 acc[8][4];
#pragma unroll
    for (int i = 0; i < 8; ++i)
#pragma unroll
        for (int j = 0; j < 4; ++j) acc[i][j] = (f32x4){0.f, 0.f, 0.f, 0.f};

    const u16* gA = A  + (size_t)(bm * 256 + srow) * Kc + sgs * 8;
    const u16* gB = Bm + (size_t)(bn * 256 + srow) * Kc + sgs * 8;

    auto stageA = [&](int buf, int half, int kt) {
#pragma unroll
        for (int iss = 0; iss < 2; ++iss) {
            const u16* g = gA + (size_t)(half * 128 + iss * 64) * Kc + kt * 64;
            const u16* d = AsB + buf * 16384 + (half * 128 + iss * 64 + (w << 3)) * 64;
            gload16(g, d);
        }
    };
    auto stageB = [&](int buf, int half, int kt) {
#pragma unroll
        for (int iss = 0; iss < 2; ++iss) {
            const u16* g = gB + (size_t)(half * 128 + iss * 64) * Kc + kt * 64;
            const u16* d = BsB + buf * 16384 + (half * 128 + iss * 64 + (w << 3)) * 64;
            gload16(g, d);
        }
    };

    bf16x8 aF[2][4][2];   // [mh][miL][ks]
    bf16x8 bF[2][2][2];   // [nh][niL][ks]

    auto readA = [&](int buf, int mh, int miL, int ks) -> bf16x8 {
        int r = mh * 128 + wm * 64 + miL * 16 + fr;
        int g = ((ks << 2) + fq) ^ fkey;
        return *reinterpret_cast<const bf16x8*>(AsB + buf * 16384 + r * 64 + g * 8);
    };
    auto readB = [&](int buf, int nh, int niL, int ks) -> bf16x8 {
        int r = nh * 128 + wn * 32 + niL * 16 + fr;
        int g = ((ks << 2) + fq) ^ fkey;
        return *reinterpret_cast<const bf16x8*>(BsB + buf * 16384 + r * 64 + g * 8);
    };

    // prologue: stage all of tile 0 (8 loads); guards happen inside ph0/ph1/ph2
    stageA(0, 0, 0); stageB(0, 0, 0); stageA(0, 1, 0); stageB(0, 1, 0);

    auto ktile = [&](int tc, auto pfc) {
        constexpr bool pf = decltype(pfc)::value;
        const int cur = tc & 1, nxt = cur ^ 1;
        // ---- phase 0: guard A0,B0(cur); stage A0',B0'; read A0,B0; MFMA q00
        if constexpr (pf) { VMW(4); stageA(nxt, 0, tc + 1); stageB(nxt, 0, tc + 1); }
        else             { VMW(4); }
        BAR();
#pragma unroll
        for (int mi = 0; mi < 4; ++mi) {
            aF[0][mi][0] = readA(cur, 0, mi, 0); aF[0][mi][1] = readA(cur, 0, mi, 1);
        }
#pragma unroll
        for (int ni = 0; ni < 2; ++ni) {
            bF[0][ni][0] = readB(cur, 0, ni, 0); bF[0][ni][1] = readB(cur, 0, ni, 1);
        }
        BAR();
        __builtin_amdgcn_s_setprio(1);
#pragma unroll
        for (int mi = 0; mi < 4; ++mi)
#pragma unroll
            for (int ni = 0; ni < 2; ++ni)
#pragma unroll
                for (int ks = 0; ks < 2; ++ks)
                    acc[mi][ni] = __builtin_amdgcn_mfma_f32_16x16x32_bf16(
                        aF[0][mi][ks], bF[0][ni][ks], acc[mi][ni], 0, 0, 0);
        __builtin_amdgcn_s_setprio(0);
        // ---- phase 1: guard A1(cur); stage A1',B1'; read A1; MFMA q10
        if constexpr (pf) { VMW(6); stageA(nxt, 1, tc + 1); stageB(nxt, 1, tc + 1); }
        else             { VMW(2); }
        BAR();
#pragma unroll
        for (int mi = 0; mi < 4; ++mi) {
            aF[1][mi][0] = readA(cur, 1, mi, 0); aF[1][mi][1] = readA(cur, 1, mi, 1);
        }
        BAR();
        __builtin_amdgcn_s_setprio(1);
#pragma unroll
        for (int mi = 0; mi < 4; ++mi)
#pragma unroll
            for (int ni = 0; ni < 2; ++ni)
#pragma unroll
                for (int ks = 0; ks < 2; ++ks)
                    acc[4 + mi][ni] = __builtin_amdgcn_mfma_f32_16x16x32_bf16(
                        aF[1][mi][ks], bF[0][ni][ks], acc[4 + mi][ni], 0, 0, 0);
        __builtin_amdgcn_s_setprio(0);
        // ---- phase 2: guard B1(cur); read B1; MFMA q11
        if constexpr (pf) { VMW(8); } else { VMW(0); }
        BAR();
#pragma unroll
        for (int ni = 0; ni < 2; ++ni) {
            bF[1][ni][0] = readB(cur, 1, ni, 0); bF[1][ni][1] = readB(cur, 1, ni, 1);
        }
        BAR();
        __builtin_amdgcn_s_setprio(1);
#pragma unroll
        for (int mi = 0; mi < 4; ++mi)
#pragma unroll
            for (int ni = 0; ni < 2; ++ni)
#pragma unroll
                for (int ks = 0; ks < 2; ++ks)
                    acc[4 + mi][2 + ni] = __builtin_amdgcn_mfma_f32_16x16x32_bf16(
                        aF[1][mi][ks], bF[1][ni][ks], acc[4 + mi][2 + ni], 0, 0, 0);
        __builtin_amdgcn_s_setprio(0);
        // ---- phase 3: reg-only; MFMA q01 (no barrier needed)
        __builtin_amdgcn_s_setprio(1);
#pragma unroll
        for (int mi = 0; mi < 4; ++mi)
#pragma unroll
            for (int ni = 0; ni < 2; ++ni)
#pragma unroll
                for (int ks = 0; ks < 2; ++ks)
                    acc[mi][2 + ni] = __builtin_amdgcn_mfma_f32_16x16x32_bf16(
                        aF[0][mi][ks], bF[1][ni][ks], acc[mi][2 + ni], 0, 0, 0);
        __builtin_amdgcn_s_setprio(0);
    };

    for (int tc = 0; tc < NT - 1; ++tc) ktile(tc, BoolC<true>{});
    ktile(NT - 1, BoolC<false>{});

    // fused LSTM epilogue: acc[mi][ni] regs = f,i,o,g of unit r, col n
    const int rB = bm * 64;
    const int nB = bn * 256;
    float zc[4], zbv[4];
#pragma unroll
    for (int ni = 0; ni < 4; ++ni) {
        int n = nB + (ni >> 1) * 128 + wn * 32 + (ni & 1) * 16 + fr;
        zc[ni] = z[n]; zbv[ni] = zb[n];
    }
#pragma unroll
    for (int mi = 0; mi < 8; ++mi) {
        const int r = rB + (mi >> 2) * 32 + wm * 16 + (mi & 3) * 4 + fq;
        const float b0 = bias[r], b1 = bias[Hd + r], b2 = bias[2 * Hd + r], b3 = bias[3 * Hd + r];
        const float* crow = c_in + (size_t)r * Bsz;
        const float* hrow = h_in + (size_t)r * Bsz;
        float* hout = out + (size_t)r * Bsz;
        float* cout = out + (size_t)Hd * Bsz + (size_t)r * Bsz;
#pragma unroll
        for (int ni = 0; ni < 4; ++ni) {
            const int n = nB + (ni >> 1) * 128 + wn * 32 + (ni & 1) * 16 + fr;
            f32x4 a = acc[mi][ni];
            float co = crow[n], ho = hrow[n];
            float fg = sigm(a[0] + b0);
            float ig = sigm(a[1] + b1);
            float og = sigm(a[2] + b2);
            float gg = tanhf(a[3] + b3);
            float i_g = ig * gg;
            float nz = 1.0f - zc[ni], nzb = 1.0f - zbv[ni];
            float cn = zc[ni] * i_g + nz * nzb * co + nz * zbv[ni] * (fg * co + i_g);
            float tc2 = tanhf(cn);
            float hn = zc[ni] * og * tc2 + nz * nzb * ho + nz * zbv[ni] * og * tc2;
            hout[n] = hn; cout[n] = cn;
        }
    }

    // z-row finalize (16 blocks with bm==0 cover all 4096 columns)
    if (bm == 0 && t < 256) {
        float* outz = out + (size_t)2 * Hd * Bsz;
        int n = bn * 256 + t;
        float s = outz[n] + bias[4096];
        float zh = (s + 1.0f) * 0.5f;
        zh = fminf(fmaxf(zh, 0.0f), 1.0f);
        outz[n] = (zh > 0.5f) ? 1.0f : 0.0f;
    }
}

extern "C" void kernel_launch(void* const* d_in, const int* in_sizes, int n_in,
                              void* d_out, int out_size, void* d_ws, size_t ws_size,
                              hipStream_t stream) {
    (void)in_sizes; (void)n_in; (void)out_size; (void)ws_size;
    const float* c    = (const float*)d_in[0];
    const float* hb   = (const float*)d_in[1];
    const float* h    = (const float*)d_in[2];
    const float* ht   = (const float*)d_in[3];
    const float* z    = (const float*)d_in[4];
    const float* zb   = (const float*)d_in[5];
    const float* U11  = (const float*)d_in[6];
    const float* U21  = (const float*)d_in[7];
    const float* W01  = (const float*)d_in[8];
    const float* bias = (const float*)d_in[9];
    float* out = (float*)d_out;

    u16* Ab = (u16*)d_ws;                          // 25.2 MB
    u16* Bb = Ab + (size_t)4096 * Kc;              // 25.2 MB

    hipFuncSetAttribute(reinterpret_cast<const void*>(gemm_fused),
                        hipFuncAttributeMaxDynamicSharedMemorySize, 131072);

    prep_A<<<6144, 256, 0, stream>>>(U11, U21, W01, Ab, out);
    prep_B<<<dim3(128, 48), 256, 0, stream>>>(hb, ht, h, z, zb, U11, U21, W01, Bb, out);
    gemm_fused<<<256, 512, 131072, stream>>>(Ab, Bb, c, h, z, zb, bias, out);
}

// Round 7
// 115.709 us; speedup vs baseline: 1.2018x; 1.0381x over previous
//
#include <hip/hip_runtime.h>
#include <hip/hip_bf16.h>
#include <math.h>

#define Hd   1024
#define Bsz  4096
#define Kc   3072      // concatenated K (3 x 1024)
#define NT   48        // K-tiles of 64

typedef unsigned short u16;
typedef __attribute__((ext_vector_type(8))) u16 u16x8;
typedef __attribute__((ext_vector_type(2))) u16 u16x2;
typedef __attribute__((ext_vector_type(4))) float f32x4;
typedef __attribute__((ext_vector_type(8))) short bf16x8;

template<bool V> struct BoolC { static constexpr bool value = V; };

__device__ inline u16 f2bf(float f) {
    __hip_bfloat16 h = __float2bfloat16(f);
    return *reinterpret_cast<u16*>(&h);
}

__device__ inline float sigm(float x) { return 1.0f / (1.0f + __expf(-x)); }

__device__ inline void gload16(const void* g, const void* s) {
    __builtin_amdgcn_global_load_lds(
        (const __attribute__((address_space(1))) void*)g,
        (__attribute__((address_space(3))) void*)s, 16, 0, 0);
}

#define BAR()   __builtin_amdgcn_s_barrier()
#define VMW(n)  asm volatile("s_waitcnt vmcnt(" #n ")" ::: "memory")
#define PRIO1() __builtin_amdgcn_s_setprio(1)
#define PRIO0() __builtin_amdgcn_s_setprio(0)

// ---------------------------------------------------------------------------
// prep_A: A_cat bf16 [4096][3072], row m' = 4*r + gate  <-  src row gate*1024+r
// Block 0 additionally zeroes the z-row accumulator region of out.
// ---------------------------------------------------------------------------
__global__ __launch_bounds__(256) void prep_A(const float* __restrict__ U11,
                                              const float* __restrict__ U21,
                                              const float* __restrict__ W01,
                                              u16* __restrict__ Ab,
                                              float* __restrict__ out) {
    if (blockIdx.x == 0) {
        float* outz = out + (size_t)2 * Hd * Bsz;
        for (int i = threadIdx.x; i < Bsz; i += 256) outz[i] = 0.0f;
    }
    int t = blockIdx.x * 256 + threadIdx.x;
    int row = t / 384;
    int kc = (t - row * 384) * 8;
    int r = row >> 2, gate = row & 3;
    int sel = kc >> 10;
    int k = kc & 1023;
    const float* src = (sel == 0) ? W01 : ((sel == 1) ? U21 : U11);
    const float4* p = reinterpret_cast<const float4*>(src + (size_t)(gate * Hd + r) * Hd + k);
    float4 v0 = p[0], v1 = p[1];
    u16x8 o;
    o[0] = f2bf(v0.x); o[1] = f2bf(v0.y); o[2] = f2bf(v0.z); o[3] = f2bf(v0.w);
    o[4] = f2bf(v1.x); o[5] = f2bf(v1.y); o[6] = f2bf(v1.z); o[7] = f2bf(v1.w);
    *reinterpret_cast<u16x8*>(Ab + (size_t)row * Kc + kc) = o;
}

// ---------------------------------------------------------------------------
// prep_B: B_catT bf16 [4096(n)][3072(k')]  (transpose + per-column z gating)
// Fused: z-row partial dot-products (w_row4096 . src) accumulated via atomicAdd.
// ---------------------------------------------------------------------------
__global__ __launch_bounds__(256) void prep_B(const float* __restrict__ hb,
                                              const float* __restrict__ ht,
                                              const float* __restrict__ hh,
                                              const float* __restrict__ z,
                                              const float* __restrict__ zb,
                                              const float* __restrict__ U11,
                                              const float* __restrict__ U21,
                                              const float* __restrict__ W01,
                                              u16* __restrict__ Bb,
                                              float* __restrict__ out) {
    __shared__ float tile[64][33];
    __shared__ float red[8][32];
    int n0 = blockIdx.x * 32;
    int kg0 = blockIdx.y * 64;
    int sel = kg0 >> 10;
    int k0 = kg0 & 1023;
    const float* src = (sel == 0) ? hb : ((sel == 1) ? ht : hh);
    const float* wsrc = (sel == 0) ? W01 : ((sel == 1) ? U21 : U11);
    int t = threadIdx.x, tx = t & 31, ty = t >> 5;
#pragma unroll
    for (int j = 0; j < 8; ++j) {
        int kk = ty * 8 + j;
        tile[kk][tx] = src[(size_t)(k0 + kk) * Bsz + n0 + tx];
    }
    __syncthreads();
    {   // bf16 transpose+gate write
        int kp = t & 31, ny = t >> 5;
#pragma unroll
        for (int j = 0; j < 4; ++j) {
            int nl = ny * 4 + j;
            int n = n0 + nl;
            float s = (sel == 0) ? 1.0f : ((sel == 1) ? z[n] : zb[n]);
            u16x2 o;
            o[0] = f2bf(tile[kp * 2][nl] * s);
            o[1] = f2bf(tile[kp * 2 + 1][nl] * s);
            *reinterpret_cast<u16x2*>(Bb + (size_t)n * Kc + kg0 + kp * 2) = o;
        }
    }
    {   // fused z-row partial
        int col = t & 31, seg = t >> 5;
        const float* w = wsrc + (size_t)4096 * 1024 + k0 + seg * 8;
        float p = 0.0f;
#pragma unroll
        for (int j = 0; j < 8; ++j) p += w[j] * tile[seg * 8 + j][col];
        red[seg][col] = p;
        __syncthreads();
        if (seg == 0) {
            float tot = 0.0f;
#pragma unroll
            for (int q = 0; q < 8; ++q) tot += red[q][col];
            int n = n0 + col;
            float sca = (sel == 0) ? 1.0f : ((sel == 1) ? z[n] : zb[n]);
            atomicAdd(out + (size_t)2 * Hd * Bsz + n, tot * sca);
        }
    }
}

// ---------------------------------------------------------------------------
// gemm_fused: 256x256 tile, BK=64, 8 waves, 16x16x32 MFMA, XOR-swizzled LDS.
// R5's verified consumption mapping (all waves walk quadrants (mh,nh) in the
// uniform order A0,B0 -> A1 -> B1) + single-barrier phases, reads at phase
// top (overlap prev phase's MFMA via wave skew), counted VMW(4) guards.
// Ledger invariant at tile entry: outstanding = {A1[T], B1[T]} (4 loads).
//   ph0: read A0,B0[T]; stage A0[T+1]; VMW(4) -> A1[T] done; BAR; MFMA q00
//   ph1: read A1[T];    stage B0[T+1]; VMW(4) -> B1[T] done; BAR; MFMA q10
//   ph2: read B1[T];    stage A1[T+1];                       BAR; MFMA q11
//   ph3: (no reads)     stage B1[T+1]; VMW(4) -> A0,B0[T+1]; BAR; MFMA q01
// Every guarded load is >=2 phases old; never drains mid-loop.
// Fused LSTM epilogue; bm==0 blocks finalize the z-row.
// ---------------------------------------------------------------------------
__global__ __launch_bounds__(512, 2) void gemm_fused(
    const u16* __restrict__ A, const u16* __restrict__ Bm,
    const float* __restrict__ c_in, const float* __restrict__ h_in,
    const float* __restrict__ z, const float* __restrict__ zb,
    const float* __restrict__ bias, float* __restrict__ out) {
    extern __shared__ __align__(16) u16 smem[];
    u16* const AsB = smem;            // [2buf][256][64] = 64 KB
    u16* const BsB = smem + 32768;    // [2buf][256][64] = 64 KB

    const int t = threadIdx.x;
    const int w = t >> 6, l = t & 63;
    const int wm = w >> 2, wn = w & 3;

    const int orig = blockIdx.x;                  // 256 wgs, bijective XCD swizzle
    const int wg = ((orig & 7) << 5) | (orig >> 3);
    const int bm = wg >> 4, bn = wg & 15;

    const int srow = t >> 3;                      // staging row within an issue
    const int sgs  = (t & 7) ^ (srow & 7);        // pre-swizzled source granule
    const int fr = l & 15, fq = l >> 4, fkey = l & 7;

    f32x4 acc[8][4];
#pragma unroll
    for (int i = 0; i < 8; ++i)
#pragma unroll
        for (int j = 0; j < 4; ++j) acc[i][j] = (f32x4){0.f, 0.f, 0.f, 0.f};

    const u16* gA = A  + (size_t)(bm * 256 + srow) * Kc + sgs * 8;
    const u16* gB = Bm + (size_t)(bn * 256 + srow) * Kc + sgs * 8;

    auto stageA = [&](int buf, int half, int kt) {
#pragma unroll
        for (int iss = 0; iss < 2; ++iss) {
            const u16* g = gA + (size_t)(half * 128 + iss * 64) * Kc + kt * 64;
            const u16* d = AsB + buf * 16384 + (half * 128 + iss * 64 + (w << 3)) * 64;
            gload16(g, d);
        }
    };
    auto stageB = [&](int buf, int half, int kt) {
#pragma unroll
        for (int iss = 0; iss < 2; ++iss) {
            const u16* g = gB + (size_t)(half * 128 + iss * 64) * Kc + kt * 64;
            const u16* d = BsB + buf * 16384 + (half * 128 + iss * 64 + (w << 3)) * 64;
            gload16(g, d);
        }
    };

    bf16x8 aF[2][4][2];   // [mh][miL][ks]
    bf16x8 bF[2][2][2];   // [nh][niL][ks]

    auto readA = [&](int buf, int mh, int miL, int ks) -> bf16x8 {
        int r = mh * 128 + wm * 64 + miL * 16 + fr;
        int g = ((ks << 2) + fq) ^ fkey;
        return *reinterpret_cast<const bf16x8*>(AsB + buf * 16384 + r * 64 + g * 8);
    };
    auto readB = [&](int buf, int nh, int niL, int ks) -> bf16x8 {
        int r = nh * 128 + wn * 32 + niL * 16 + fr;
        int g = ((ks << 2) + fq) ^ fkey;
        return *reinterpret_cast<const bf16x8*>(BsB + buf * 16384 + r * 64 + g * 8);
    };

#define MFMAQ(mh, nh)                                                         \
    PRIO1();                                                                  \
    _Pragma("unroll")                                                         \
    for (int mi = 0; mi < 4; ++mi)                                            \
        _Pragma("unroll")                                                     \
        for (int ni = 0; ni < 2; ++ni)                                        \
            _Pragma("unroll")                                                 \
            for (int ks = 0; ks < 2; ++ks)                                    \
                acc[(mh)*4 + mi][(nh)*2 + ni] =                               \
                    __builtin_amdgcn_mfma_f32_16x16x32_bf16(                  \
                        aF[mh][mi][ks], bF[nh][ni][ks],                       \
                        acc[(mh)*4 + mi][(nh)*2 + ni], 0, 0, 0);              \
    PRIO0()

    // prologue: stage tile 0 halves A0,B0,A1,B1; ensure A0,B0 complete
    stageA(0, 0, 0); stageB(0, 0, 0); stageA(0, 1, 0); stageB(0, 1, 0);
    VMW(4); BAR();

    auto ktile = [&](int T, auto lastc) {
        constexpr bool last = decltype(lastc)::value;
        const int p = T & 1, q2 = p ^ 1;
        // ---- ph0: reads A0,B0[T]; stage A0[T+1]; guard A1[T]; MFMA q00
#pragma unroll
        for (int j = 0; j < 4; ++j) {
            aF[0][j][0] = readA(p, 0, j, 0); aF[0][j][1] = readA(p, 0, j, 1);
        }
#pragma unroll
        for (int j = 0; j < 2; ++j) {
            bF[0][j][0] = readB(p, 0, j, 0); bF[0][j][1] = readB(p, 0, j, 1);
        }
        if constexpr (!last) { stageA(q2, 0, T + 1); VMW(4); } else { VMW(2); }
        BAR();
        MFMAQ(0, 0);
        // ---- ph1: reads A1[T]; stage B0[T+1]; guard B1[T]; MFMA q10
#pragma unroll
        for (int j = 0; j < 4; ++j) {
            aF[1][j][0] = readA(p, 1, j, 0); aF[1][j][1] = readA(p, 1, j, 1);
        }
        if constexpr (!last) { stageB(q2, 0, T + 1); VMW(4); } else { VMW(0); }
        BAR();
        MFMAQ(1, 0);
        // ---- ph2: reads B1[T]; stage A1[T+1]; MFMA q11
#pragma unroll
        for (int j = 0; j < 2; ++j) {
            bF[1][j][0] = readB(p, 1, j, 0); bF[1][j][1] = readB(p, 1, j, 1);
        }
        if constexpr (!last) stageA(q2, 1, T + 1);
        BAR();
        MFMAQ(1, 1);
        // ---- ph3: no reads; stage B1[T+1]; guard A0,B0[T+1]; MFMA q01
        if constexpr (!last) { stageB(q2, 1, T + 1); VMW(4); }
        BAR();
        MFMAQ(0, 1);
    };

    for (int T = 0; T < NT - 1; ++T) ktile(T, BoolC<false>{});
    ktile(NT - 1, BoolC<true>{});

    // fused LSTM epilogue: acc[mi][ni] regs = f,i,o,g of unit r, col n
    const int rB = bm * 64;
    const int nB = bn * 256;
    float zc[4], zbv[4];
#pragma unroll
    for (int ni = 0; ni < 4; ++ni) {
        int n = nB + (ni >> 1) * 128 + wn * 32 + (ni & 1) * 16 + fr;
        zc[ni] = z[n]; zbv[ni] = zb[n];
    }
#pragma unroll
    for (int mi = 0; mi < 8; ++mi) {
        const int r = rB + (mi >> 2) * 32 + wm * 16 + (mi & 3) * 4 + fq;
        const float b0 = bias[r], b1 = bias[Hd + r], b2 = bias[2 * Hd + r], b3 = bias[3 * Hd + r];
        const float* crow = c_in + (size_t)r * Bsz;
        const float* hrow = h_in + (size_t)r * Bsz;
        float* hout = out + (size_t)r * Bsz;
        float* cout = out + (size_t)Hd * Bsz + (size_t)r * Bsz;
#pragma unroll
        for (int ni = 0; ni < 4; ++ni) {
            const int n = nB + (ni >> 1) * 128 + wn * 32 + (ni & 1) * 16 + fr;
            f32x4 a = acc[mi][ni];
            float co = crow[n], ho = hrow[n];
            float fg = sigm(a[0] + b0);
            float ig = sigm(a[1] + b1);
            float og = sigm(a[2] + b2);
            float gg = tanhf(a[3] + b3);
            float i_g = ig * gg;
            float nz = 1.0f - zc[ni], nzb = 1.0f - zbv[ni];
            float cn = zc[ni] * i_g + nz * nzb * co + nz * zbv[ni] * (fg * co + i_g);
            float tc2 = tanhf(cn);
            float hn = zc[ni] * og * tc2 + nz * nzb * ho + nz * zbv[ni] * og * tc2;
            hout[n] = hn; cout[n] = cn;
        }
    }

    // z-row finalize (16 blocks with bm==0 cover all 4096 columns)
    if (bm == 0 && t < 256) {
        float* outz = out + (size_t)2 * Hd * Bsz;
        int n = bn * 256 + t;
        float s = outz[n] + bias[4096];
        float zh = (s + 1.0f) * 0.5f;
        zh = fminf(fmaxf(zh, 0.0f), 1.0f);
        outz[n] = (zh > 0.5f) ? 1.0f : 0.0f;
    }
#undef MFMAQ
}

extern "C" void kernel_launch(void* const* d_in, const int* in_sizes, int n_in,
                              void* d_out, int out_size, void* d_ws, size_t ws_size,
                              hipStream_t stream) {
    (void)in_sizes; (void)n_in; (void)out_size; (void)ws_size;
    const float* c    = (const float*)d_in[0];
    const float* hb   = (const float*)d_in[1];
    const float* h    = (const float*)d_in[2];
    const float* ht   = (const float*)d_in[3];
    const float* z    = (const float*)d_in[4];
    const float* zb   = (const float*)d_in[5];
    const float* U11  = (const float*)d_in[6];
    const float* U21  = (const float*)d_in[7];
    const float* W01  = (const float*)d_in[8];
    const float* bias = (const float*)d_in[9];
    float* out = (float*)d_out;

    u16* Ab = (u16*)d_ws;                          // 25.2 MB
    u16* Bb = Ab + (size_t)4096 * Kc;              // 25.2 MB

    hipFuncSetAttribute(reinterpret_cast<const void*>(gemm_fused),
                        hipFuncAttributeMaxDynamicSharedMemorySize, 131072);

    prep_A<<<6144, 256, 0, stream>>>(U11, U21, W01, Ab, out);
    prep_B<<<dim3(128, 48), 256, 0, stream>>>(hb, ht, h, z, zb, U11, U21, W01, Bb, out);
    gemm_fused<<<256, 512, 131072, stream>>>(Ab, Bb, c, h, z, zb, bias, out);
}